// Round 1
// baseline (311.513 us; speedup 1.0000x reference)
//
#include <hip/hip_runtime.h>

// SlotFillingCoachModel: ragged slot-span mean pooling + linear classifier.
// out[b,n,l] = (1/cnt) * sum_{r=beg..beg+len} hs[b,r,:] . W[:,l] + bias[l]

#define BS    64
#define SEQ   1024
#define DIM   800
#define NSLOT 64
#define NLAB  72
#define SPB   8              // slots per block
#define KTILE 160            // K-tile for W staging (divides 800)
#define NC    (DIM / 4)      // 200 float4 per row

__global__ __launch_bounds__(256, 2) void slot_clf_kernel(
    const float* __restrict__ hs,      // (BS, SEQ, DIM)
    const int*   __restrict__ begins,  // (BS, NSLOT)
    const int*   __restrict__ lens,    // (BS, NSLOT)
    const float* __restrict__ W,       // (DIM, NLAB)
    const float* __restrict__ bias,    // (NLAB)
    float*       __restrict__ out)     // (BS, NSLOT, NLAB)
{
    __shared__ float pool[SPB][DIM];       // 25.6 KB
    __shared__ float Wt[KTILE * NLAB];     // 46.1 KB, same row-major layout as W
    __shared__ int s_begin[SPB];
    __shared__ int s_count[SPB];

    const int t  = threadIdx.x;
    const int b  = blockIdx.x >> 3;               // / (NSLOT/SPB)
    const int n0 = (blockIdx.x & 7) * SPB;

    if (t < SPB) {
        int idx = b * NSLOT + n0 + t;
        s_begin[t] = begins[idx];
        s_count[t] = lens[idx] + 1;               // inclusive end -> cnt in 1..8
    }
    __syncthreads();

    // ---- Phase 1: ragged mean-pool SPB slots into LDS (float4 coalesced) ----
    for (int i = t; i < SPB * NC; i += 256) {
        int s = i / NC;
        int c = i - s * NC;
        int beg = s_begin[s];
        int cnt = s_count[s];
        const float4* rowp = (const float4*)(hs + ((size_t)b * SEQ + beg) * DIM) + c;
        float4 a0 = make_float4(0.f, 0.f, 0.f, 0.f);
        float4 a1 = make_float4(0.f, 0.f, 0.f, 0.f);
        int r = 0;
        // dual accumulators: two independent load chains in flight
        for (; r + 2 <= cnt; r += 2) {
            float4 v0 = rowp[(size_t)r * NC];
            float4 v1 = rowp[(size_t)(r + 1) * NC];
            a0.x += v0.x; a0.y += v0.y; a0.z += v0.z; a0.w += v0.w;
            a1.x += v1.x; a1.y += v1.y; a1.z += v1.z; a1.w += v1.w;
        }
        if (r < cnt) {
            float4 v0 = rowp[(size_t)r * NC];
            a0.x += v0.x; a0.y += v0.y; a0.z += v0.z; a0.w += v0.w;
        }
        float inv = 1.0f / (float)cnt;
        pool[s][c * 4 + 0] = (a0.x + a1.x) * inv;
        pool[s][c * 4 + 1] = (a0.y + a1.y) * inv;
        pool[s][c * 4 + 2] = (a0.z + a1.z) * inv;
        pool[s][c * 4 + 3] = (a0.w + a1.w) * inv;
    }

    // ---- Phase 2: logits = pool @ W + bias ----
    // wave w handles slots {2w, 2w+1}; lane handles label `lane`
    // (and label 64+lane for lane<8). pool reads are wave-uniform (broadcast),
    // W reads are lane-consecutive (2 lanes/bank -> conflict-free).
    const int wave = t >> 6;
    const int lane = t & 63;
    const int s0   = wave * 2;
    float acc00 = 0.f, acc10 = 0.f, acc01 = 0.f, acc11 = 0.f;

    for (int k0 = 0; k0 < DIM; k0 += KTILE) {
        __syncthreads();   // previous tile consumed (and, 1st iter, pool ready)
        const float* Wsrc = W + (size_t)k0 * NLAB;
        for (int i = t; i < KTILE * NLAB; i += 256)
            Wt[i] = Wsrc[i];                      // contiguous, coalesced
        __syncthreads();

        #pragma unroll 4
        for (int dd = 0; dd < KTILE; ++dd) {
            float p0 = pool[s0][k0 + dd];
            float p1 = pool[s0 + 1][k0 + dd];
            float w0 = Wt[dd * NLAB + lane];
            acc00 = fmaf(p0, w0, acc00);
            acc10 = fmaf(p1, w0, acc10);
            if (lane < NLAB - 64) {               // labels 64..71
                float w1 = Wt[dd * NLAB + 64 + lane];
                acc01 = fmaf(p0, w1, acc01);
                acc11 = fmaf(p1, w1, acc11);
            }
        }
    }

    float* outb = out + ((size_t)b * NSLOT + n0) * NLAB;
    outb[(s0 + 0) * NLAB + lane] = acc00 + bias[lane];
    outb[(s0 + 1) * NLAB + lane] = acc10 + bias[lane];
    if (lane < NLAB - 64) {
        outb[(s0 + 0) * NLAB + 64 + lane] = acc01 + bias[64 + lane];
        outb[(s0 + 1) * NLAB + 64 + lane] = acc11 + bias[64 + lane];
    }
}

extern "C" void kernel_launch(void* const* d_in, const int* in_sizes, int n_in,
                              void* d_out, int out_size, void* d_ws, size_t ws_size,
                              hipStream_t stream) {
    const float* hs     = (const float*)d_in[0];
    const int*   begins = (const int*)  d_in[1];
    const int*   lens   = (const int*)  d_in[2];
    const float* W      = (const float*)d_in[3];
    const float* bias   = (const float*)d_in[4];
    float*       out    = (float*)d_out;

    slot_clf_kernel<<<dim3(BS * (NSLOT / SPB)), dim3(256), 0, stream>>>(
        hs, begins, lens, W, bias, out);
}

// Round 3
// 262.857 us; speedup vs baseline: 1.1851x; 1.1851x over previous
//
#include <hip/hip_runtime.h>

// SlotFillingCoachModel: ragged slot-span mean pooling + linear classifier.
// out[b,n,l] = (1/cnt) * sum_{r=beg..beg+len} hs[b,r,:] . W[:,l] + bias[l]
//
// R3: same as R2 but with the MFMA k-stride fixed: one 16x16x32 k-step
// consumes 32 bf16 = FOUR short8 units -> fragment index is [4*kk], not [2*kk].

#define BS    64
#define SEQ   1024
#define DIM   800
#define NSLOT 64
#define NLAB  72
#define SPB   8               // slots per block
#define NC    (DIM / 4)       // 200 float4 per row
#define PS    808             // pool LDS row stride (bf16 elems): 2-way banks, 16B-aligned
#define NTROW 80              // WT rows in ws (72 real + 8 zero)
#define KK    (DIM / 32)      // 25 MFMA k-steps

typedef __attribute__((ext_vector_type(8))) short short8;   // bf16 A/B frag (4 VGPRs)
typedef __attribute__((ext_vector_type(4))) float float4v;  // fp32 C/D frag

static __device__ inline unsigned short f2bf(float f) {
    unsigned u = __builtin_bit_cast(unsigned, f);
    u += 0x7fffu + ((u >> 16) & 1u);          // round-to-nearest-even
    return (unsigned short)(u >> 16);
}

// ---- prep: WT[n][k] = bf16(W[k][n]), rows 72..79 zeroed ----
__global__ void prep_wt_kernel(const float* __restrict__ W, unsigned short* __restrict__ wt) {
    int i = blockIdx.x * 256 + threadIdx.x;   // i = n*800 + k
    if (i >= NTROW * DIM) return;
    int n = i / DIM;
    int k = i - n * DIM;
    float v = (n < NLAB) ? W[k * NLAB + n] : 0.0f;
    wt[i] = f2bf(v);
}

__global__ __launch_bounds__(320, 3) void slot_clf_kernel(
    const float*          __restrict__ hs,      // (BS, SEQ, DIM)
    const int*            __restrict__ begins,  // (BS, NSLOT)
    const int*            __restrict__ lens,    // (BS, NSLOT)
    const unsigned short* __restrict__ wt,      // (NTROW, DIM) bf16, transposed W
    const float*          __restrict__ bias,    // (NLAB)
    float*                __restrict__ out)     // (BS, NSLOT, NLAB)
{
    __shared__ unsigned short poolb[16 * PS];   // 25.9 KB, rows 8..15 zero (M-pad)
    __shared__ int s_begin[SPB];
    __shared__ int s_count[SPB];

    const int t  = threadIdx.x;
    const int b  = blockIdx.x >> 3;
    const int n0 = (blockIdx.x & 7) * SPB;      // first slot of this block

    if (t < SPB) {
        int idx = b * NSLOT + n0 + t;
        s_begin[t] = begins[idx];
        s_count[t] = lens[idx] + 1;             // inclusive end -> cnt in 1..8
    }
    // zero M-pad rows 8..15 (keep MFMA inputs finite)
    {
        unsigned* pz = (unsigned*)(poolb + 8 * PS);
        for (int i = t; i < 8 * PS / 2; i += 320) pz[i] = 0u;
    }
    __syncthreads();

    // ---- Phase 1: ragged mean-pool into bf16 LDS (float4-coalesced HBM reads) ----
    for (int i = t; i < SPB * NC; i += 320) {   // exactly 5 iterations
        int s = i / NC;
        int c = i - s * NC;
        int beg = s_begin[s];
        int cnt = s_count[s];
        const float4* rowp = (const float4*)(hs + ((size_t)b * SEQ + beg) * DIM) + c;
        float4 a0 = make_float4(0.f, 0.f, 0.f, 0.f);
        float4 a1 = make_float4(0.f, 0.f, 0.f, 0.f);
        int r = 0;
        for (; r + 2 <= cnt; r += 2) {          // dual independent load chains
            float4 v0 = rowp[(size_t)r * NC];
            float4 v1 = rowp[(size_t)(r + 1) * NC];
            a0.x += v0.x; a0.y += v0.y; a0.z += v0.z; a0.w += v0.w;
            a1.x += v1.x; a1.y += v1.y; a1.z += v1.z; a1.w += v1.w;
        }
        if (r < cnt) {
            float4 v0 = rowp[(size_t)r * NC];
            a0.x += v0.x; a0.y += v0.y; a0.z += v0.z; a0.w += v0.w;
        }
        float inv = 1.0f / (float)cnt;
        ushort4 pk;
        pk.x = f2bf((a0.x + a1.x) * inv);
        pk.y = f2bf((a0.y + a1.y) * inv);
        pk.z = f2bf((a0.z + a1.z) * inv);
        pk.w = f2bf((a0.w + a1.w) * inv);
        *(ushort4*)(poolb + s * PS + 4 * c) = pk;   // 8B store, 8B-aligned
    }
    __syncthreads();

    // ---- Phase 2: logits via MFMA. wave w <-> label tile w (n = 16w .. 16w+15) ----
    const int wave = t >> 6;        // 0..4
    const int lane = t & 63;
    const int col  = lane & 15;     // = n_local (B/C col), also A row m for loads
    const int quad = lane >> 4;     // k-group: k = quad*8 + j

    const int n = wave * 16 + col;  // global label (>=72 on tile 4 -> zero rows)
    // A-frag: poolb[m=col][32*kk + 8*quad + j]
    const short8* ap = (const short8*)(poolb + col * PS + 8 * quad);
    // B-frag: wt[n][32*kk + 8*quad + j]
    const short8* bp = (const short8*)(wt + (size_t)n * DIM + 8 * quad);

    float4v acc = {0.f, 0.f, 0.f, 0.f};
    #pragma unroll 5
    for (int kk = 0; kk < KK; ++kk) {
        short8 a   = ap[4 * kk];    // k-step stride = 32 shorts = 4 short8
        short8 bfr = bp[4 * kk];
        acc = __builtin_amdgcn_mfma_f32_16x16x32_bf16(a, bfr, acc, 0, 0, 0);
    }

    // C/D layout: col = lane&15 (label), row m = quad*4 + reg (slot, valid m<8)
    if (n < NLAB) {
        float bv = bias[n];
        float* outb = out + ((size_t)b * NSLOT + n0) * NLAB + n;
        #pragma unroll
        for (int r = 0; r < 4; ++r) {
            int m = quad * 4 + r;
            if (m < SPB) outb[(size_t)m * NLAB] = acc[r] + bv;
        }
    }
}

extern "C" void kernel_launch(void* const* d_in, const int* in_sizes, int n_in,
                              void* d_out, int out_size, void* d_ws, size_t ws_size,
                              hipStream_t stream) {
    const float* hs     = (const float*)d_in[0];
    const int*   begins = (const int*)  d_in[1];
    const int*   lens   = (const int*)  d_in[2];
    const float* W      = (const float*)d_in[3];
    const float* bias   = (const float*)d_in[4];
    float*       out    = (float*)d_out;
    unsigned short* wt  = (unsigned short*)d_ws;   // 80*800*2 = 128 KB of ws

    prep_wt_kernel<<<dim3((NTROW * DIM + 255) / 256), dim3(256), 0, stream>>>(W, wt);
    slot_clf_kernel<<<dim3(BS * (NSLOT / SPB)), dim3(320), 0, stream>>>(
        hs, begins, lens, wt, bias, out);
}